// Round 8
// baseline (102.514 us; speedup 1.0000x reference)
//
#include <hip/hip_runtime.h>
#include <stdint.h>

#define INDIM   1024
#define OUTDIM  1024
#define BM 64
#define BN 64
#define BK 64
#define KTILES (INDIM / BK)    // 16

typedef __attribute__((ext_vector_type(8))) short  short8;   // 8 bf16 (4 VGPRs)
typedef __attribute__((ext_vector_type(4))) float  floatx4;  // MFMA acc

// ---------------- build dense W^T (fp32, handles duplicate (i,o) by add) ----
__global__ void k_scatter_w(const int* __restrict__ ind_in, const int* __restrict__ ind_out,
                            const float* __restrict__ w, float* __restrict__ W32T, int nnz) {
    int k = blockIdx.x * 256 + threadIdx.x;
    if (k < nnz)
        atomicAdd(&W32T[(size_t)ind_out[k] * INDIM + ind_in[k]], w[k]);
}

// fp32 pair -> packed bf16x2 (RNE)
__device__ __forceinline__ uint32_t bf16pack(float x, float y) {
    uint32_t ux = __float_as_uint(x);
    ux = ((ux + 0x7FFFu + ((ux >> 16) & 1u)) >> 16) & 0xFFFFu;   // low  = x
    uint32_t uy = __float_as_uint(y);
    uy = (uy + 0x7FFFu + ((uy >> 16) & 1u)) & 0xFFFF0000u;       // high = y
    return ux | uy;
}

__device__ __forceinline__ uint4 pack8(float4 a, float4 b) {
    return make_uint4(bf16pack(a.x, a.y), bf16pack(a.z, a.w),
                      bf16pack(b.x, b.y), bf16pack(b.z, b.w));
}

// ---------------- fused bf16 MFMA GEMM: C = A(fp32) * W32T(fp32)^T + bias --
// R8: conversion fused into staging (R7's separate k_convert was 30 MB of
// traffic + a dispatch). Geometry identical to R7's winner: 64x64x64 tile,
// 1024 blocks = 4 blocks/CU (R6 showed 1 block/CU stalls at MfmaUtil 5.7%),
// 4 waves, wave tile 32x32 = 2x2 of 16x16x32, XOR chunk swizzle (measured
// SQ_LDS_BANK_CONFLICT = 0). bf16pack VALU lands on the idle vector pipe,
// co-scheduled with MFMA + LDS (m114). Verified layouts (guide §3):
// A-frag m=lane&15,k=quad*8+j; B-frag n=lane&15; C/D col=lane&15,row=quad*4+r.
__global__ __launch_bounds__(256, 4) void k_gemm(
    const float* __restrict__ A32,    // [M][1024] fp32 row-major (input)
    const float* __restrict__ W32T,   // [1024 n][1024 k] fp32 row-major
    const float* __restrict__ bias,
    float* __restrict__ C, int M)
{
    __shared__ ushort lA[BM * BK];   // 8 KB
    __shared__ ushort lB[BN * BK];   // 8 KB

    const int t      = threadIdx.x;
    const int w      = t >> 6;
    const int L      = t & 63;
    const int lane15 = L & 15;
    const int lane7  = L & 7;
    const int quad   = L >> 4;
    const int wm     = w >> 1, wn = w & 1;

    // XCD-aware swizzle (bid&7 = XCD round-robin): XCD x owns A rows
    // [x*512, x*512+512) -> per-XCD hot set = 2 MB A + 4 MB W, mostly L2.
    const int bid = blockIdx.x;
    const int bm0 = ((bid & 7) * 8 + (bid >> 7)) * BM;
    const int bn0 = ((bid >> 3) & 15) * BN;

    // staging: thread t stages 8-elem chunk j8 of rows srow and srow+32 of
    // both tiles. slot = t&7; stored global chunk = slot ^ (row&7); rows 32
    // apart share (row&7) -> one j8 per thread.
    const int srow = t >> 3;                       // 0..31
    const int j8   = (t & 7) ^ (srow & 7);

    const float* Abase = A32  + (size_t)bm0 * INDIM;
    const float* Bbase = W32T + (size_t)bn0 * INDIM;

    floatx4 acc[2][2] = {};

    for (int kt = 0; kt < KTILES; ++kt) {
        const int gcol = kt * BK + j8 * 8;
        const float* pa0 = Abase + (size_t)srow        * INDIM + gcol;
        const float* pa1 = Abase + (size_t)(srow + 32) * INDIM + gcol;
        const float* pb0 = Bbase + (size_t)srow        * INDIM + gcol;
        const float* pb1 = Bbase + (size_t)(srow + 32) * INDIM + gcol;
        uint4 va0 = pack8(*(const float4*)pa0, *(const float4*)(pa0 + 4));
        uint4 va1 = pack8(*(const float4*)pa1, *(const float4*)(pa1 + 4));
        uint4 vb0 = pack8(*(const float4*)pb0, *(const float4*)(pb0 + 4));
        uint4 vb1 = pack8(*(const float4*)pb1, *(const float4*)(pb1 + 4));
        __syncthreads();                 // previous iter done reading LDS
        *(uint4*)(lA + (size_t)t * 8)         = va0;
        *(uint4*)(lA + (size_t)(t + 256) * 8) = va1;
        *(uint4*)(lB + (size_t)t * 8)         = vb0;
        *(uint4*)(lB + (size_t)(t + 256) * 8) = vb1;
        __syncthreads();                 // writes visible

        #pragma unroll
        for (int ks = 0; ks < 2; ++ks) {
            const int koff = (((ks * 4 + quad) ^ lane7) * 8);
            short8 af[2], bf[2];
            #pragma unroll
            for (int tm = 0; tm < 2; ++tm)
                af[tm] = *(const short8*)(lA + (wm * 32 + tm * 16 + lane15) * 64 + koff);
            #pragma unroll
            for (int tn = 0; tn < 2; ++tn)
                bf[tn] = *(const short8*)(lB + (wn * 32 + tn * 16 + lane15) * 64 + koff);
            #pragma unroll
            for (int tm = 0; tm < 2; ++tm)
                #pragma unroll
                for (int tn = 0; tn < 2; ++tn)
                    acc[tm][tn] = __builtin_amdgcn_mfma_f32_16x16x32_bf16(
                        af[tm], bf[tn], acc[tm][tn], 0, 0, 0);
        }
    }

    // ---- epilogue: bias + store ----
    #pragma unroll
    for (int tm = 0; tm < 2; ++tm) {
        #pragma unroll
        for (int tn = 0; tn < 2; ++tn) {
            const int col = bn0 + wn * 32 + tn * 16 + lane15;
            const float bv = bias[col];
            #pragma unroll
            for (int r = 0; r < 4; ++r) {
                const int row = bm0 + wm * 32 + tm * 16 + quad * 4 + r;
                C[(size_t)row * OUTDIM + col] = acc[tm][tn][r] + bv;
            }
        }
    }
}

// ---------------- launcher ----------------
extern "C" void kernel_launch(void* const* d_in, const int* in_sizes, int n_in,
                              void* d_out, int out_size, void* d_ws, size_t ws_size,
                              hipStream_t stream) {
    const float* input  = (const float*)d_in[0];
    const float* weight = (const float*)d_in[1];
    const float* bias   = (const float*)d_in[2];
    const int*   ind_in  = (const int*)d_in[3];
    const int*   ind_out = (const int*)d_in[4];
    float* out = (float*)d_out;

    const int nnz = in_sizes[1];
    const int M   = out_size / OUTDIM;      // 4096 (multiple of BM)

    float* W32T = (float*)d_ws;             // 4 MB @ 0 — only ws use now

    (void)hipMemsetAsync(W32T, 0, (size_t)OUTDIM * INDIM * sizeof(float), stream);
    k_scatter_w<<<(nnz + 255) / 256, 256, 0, stream>>>(ind_in, ind_out, weight, W32T, nnz);
    k_gemm<<<(M / BM) * (OUTDIM / BN), 256, 0, stream>>>(input, W32T, bias, out, M);
}